// Round 2
// baseline (3673.854 us; speedup 1.0000x reference)
//
#include <hip/hip_runtime.h>
#include <hip/hip_bf16.h>
#include <math.h>

#define L 4096
#define C 256
#define B 8

// ---------------- Kernel 1: mask compaction (single block) ----------------
__global__ __launch_bounds__(256) void compact_mask(
    const int* __restrict__ mask, int* __restrict__ counts,
    int* __restrict__ maskedOrig, int* __restrict__ unmaskOrig,
    int* __restrict__ posOf)
{
    __shared__ int smM[256], smU[256];
    int t = threadIdx.x;
    int flags[16];
    int cm = 0, cu = 0;
    for (int k = 0; k < 16; ++k) {
        int l = t * 16 + k;
        int f = mask[l] > 0;
        flags[k] = f;
        cm += f; cu += !f;
    }
    smM[t] = cm; smU[t] = cu;
    __syncthreads();
    for (int off = 1; off < 256; off <<= 1) {
        int vM = 0, vU = 0;
        if (t >= off) { vM = smM[t - off]; vU = smU[t - off]; }
        __syncthreads();
        smM[t] += vM; smU[t] += vU;
        __syncthreads();
    }
    if (t == 255) { counts[0] = smM[255]; counts[1] = smU[255]; }
    int pm = smM[t] - cm, pu = smU[t] - cu;
    for (int k = 0; k < 16; ++k) {
        int l = t * 16 + k;
        if (flags[k]) { maskedOrig[pm] = l; posOf[l] = pm; pm++; }
        else          { unmaskOrig[pu] = l; posOf[l] = pu; pu++; }
    }
}

// ---------------- Kernel 2: normalize rows of F_s, write transposed+compacted ----------------
// fsn layout: (b, row, c) with rows [0..Nm) = masked pixels (ascending l), [Nm..L) = unmasked.
__global__ __launch_bounds__(256) void norm_transpose(
    const float* __restrict__ input, const int* __restrict__ mask,
    const int* __restrict__ counts, const int* __restrict__ posOf,
    float* __restrict__ fsn)
{
    int bx = blockIdx.x;           // 0..1023
    int b = bx >> 7;
    int l0 = (bx & 127) * 32;
    __shared__ float tile[256 * 33];
    __shared__ float part[8 * 33];
    __shared__ float denom[32];
    __shared__ int   rowdst[32];
    int t = threadIdx.x;
    int lsub = t & 31, cg = t >> 5;     // cg 0..7
    for (int cc = 0; cc < 256; cc += 8) {
        int c = cc + cg;
        tile[c * 33 + lsub] = input[((size_t)(b * 512 + 256 + c)) * L + l0 + lsub];
    }
    __syncthreads();
    float s = 0.f;
    for (int c = cg; c < 256; c += 8) { float v = tile[c * 33 + lsub]; s = fmaf(v, v, s); }
    part[cg * 33 + lsub] = s;
    __syncthreads();
    if (t < 32) {
        float s2 = 0.f;
        for (int g = 0; g < 8; ++g) s2 += part[g * 33 + t];
        denom[t] = sqrtf(s2) + 1e-8f;
        int l = l0 + t;
        int Nm = counts[0];
        rowdst[t] = (mask[l] > 0) ? posOf[l] : (Nm + posOf[l]);
    }
    __syncthreads();
    for (int ls = 0; ls < 32; ++ls) {
        int r = rowdst[ls];
        float d = denom[ls];
        fsn[((size_t)b * L + r) * C + t] = tile[t * 33 + ls] / d;
    }
}

// ---------------- Kernel 3: sim GEMM (masked x unmasked) + fused argmax ----------------
__global__ __launch_bounds__(256) void sim_argmax(
    const float* __restrict__ fsn, const int* __restrict__ counts,
    const int* __restrict__ maskedOrig, const int* __restrict__ unmaskOrig,
    int* __restrict__ idxmap)
{
    int b = blockIdx.y;
    int m0 = blockIdx.x * 64;
    int Nm = counts[0], Nu = counts[1];
    if (m0 >= Nm) return;
    const float* base = fsn + (size_t)b * L * C;
    __shared__ float As[64][65];
    __shared__ float Bs[64][65];
    __shared__ float rv[64][17];
    __shared__ int   rj[64][17];
    int t = threadIdx.x;
    int tx = t & 15, ty = t >> 4;
    float bestv[4]; int bestj[4];
#pragma unroll
    for (int q = 0; q < 4; ++q) { bestv[q] = -2e9f; bestj[q] = 0; }
    int ntiles = (Nu + 63) >> 6;
    for (int nt = 0; nt < ntiles; ++nt) {
        int n0 = nt * 64;
        float cacc[4][4];
#pragma unroll
        for (int i = 0; i < 4; ++i)
#pragma unroll
            for (int j = 0; j < 4; ++j) cacc[i][j] = 0.f;
        for (int kc = 0; kc < 4; ++kc) {
            __syncthreads();
#pragma unroll
            for (int rep = 0; rep < 16; ++rep) {
                int idx = rep * 256 + t;
                int i = idx >> 6, k = idx & 63;
                As[i][k] = base[(size_t)(m0 + i) * C + kc * 64 + k];
                int j = n0 + i;
                Bs[i][k] = (j < Nu) ? base[(size_t)(Nm + j) * C + kc * 64 + k] : 0.f;
            }
            __syncthreads();
#pragma unroll
            for (int k = 0; k < 64; ++k) {
                float a[4], bb[4];
#pragma unroll
                for (int q = 0; q < 4; ++q) { a[q] = As[ty * 4 + q][k]; bb[q] = Bs[tx * 4 + q][k]; }
#pragma unroll
                for (int i = 0; i < 4; ++i)
#pragma unroll
                    for (int j = 0; j < 4; ++j) cacc[i][j] = fmaf(a[i], bb[j], cacc[i][j]);
            }
        }
#pragma unroll
        for (int i = 0; i < 4; ++i)
#pragma unroll
            for (int j = 0; j < 4; ++j) {
                int jj = n0 + tx * 4 + j;
                float v = cacc[i][j];
                if (jj < Nu && (v > bestv[i] || (v == bestv[i] && jj < bestj[i]))) {
                    bestv[i] = v; bestj[i] = jj;
                }
            }
    }
    __syncthreads();
#pragma unroll
    for (int i = 0; i < 4; ++i) { rv[ty * 4 + i][tx] = bestv[i]; rj[ty * 4 + i][tx] = bestj[i]; }
    __syncthreads();
    if (t < 64) {
        float bv = rv[t][0]; int bj = rj[t][0];
        for (int x = 1; x < 16; ++x) {
            float v = rv[t][x]; int j = rj[t][x];
            if (v > bv || (v == bv && j < bj)) { bv = v; bj = j; }
        }
        int m = m0 + t;
        if (m < Nm) idxmap[b * L + maskedOrig[m]] = unmaskOrig[bj];
    }
}

// ---------------- Kernel 4: gather + fuse ----------------
__global__ __launch_bounds__(256) void fuse_kernel(
    const float* __restrict__ input, const int* __restrict__ mask,
    const int* __restrict__ idxmap, float* __restrict__ fuse)
{
    int i = blockIdx.x * 256 + threadIdx.x;  // 0 .. 8*256*4096-1
    int l = i & 4095;
    int c = (i >> 12) & 255;
    int b = i >> 20;
    float v = 0.f;
    if (mask[l] > 0) {
        int n = idxmap[(b << 12) + l];
        const float* fc = input + ((size_t)(b * 512 + c)) * L;
        v = fc[l] * fc[n];
    }
    fuse[i] = v;
}

// ---------------- Kernel 5: conv1 (512->256) + instance norm + relu ----------------
__global__ __launch_bounds__(256) void conv1_inorm_relu(
    const float* __restrict__ input, const float* __restrict__ fuse,
    const float* __restrict__ W1, float* __restrict__ h)
{
    int b = blockIdx.y;
    int co0 = blockIdx.x * 4;
    __shared__ float plane[66 * 67];
    __shared__ float wbuf[36];
    __shared__ float red[256];
    __shared__ float red2[256];
    __shared__ float bc[2];
    int t = threadIdx.x;
    int tx = t & 15, ty = t >> 4;
    int x0 = tx * 4, y0 = ty * 4;
    float acc[4][16];
#pragma unroll
    for (int c = 0; c < 4; ++c)
#pragma unroll
        for (int q = 0; q < 16; ++q) acc[c][q] = 0.f;
    for (int i = t; i < 66 * 67; i += 256) plane[i] = 0.f;
    for (int ci = 0; ci < 512; ++ci) {
        const float* src = (ci < 256) ? input + ((size_t)(b * 512 + ci)) * L
                                      : fuse + ((size_t)(b * 256 + ci - 256)) * L;
        __syncthreads();
#pragma unroll
        for (int rep = 0; rep < 4; ++rep) {
            int idx = rep * 256 + t;            // float4 units
            int y = idx >> 4, x4 = idx & 15;
            float4 v = *reinterpret_cast<const float4*>(src + y * 64 + x4 * 4);
            float* dst = &plane[(y + 1) * 67 + 1 + x4 * 4];
            dst[0] = v.x; dst[1] = v.y; dst[2] = v.z; dst[3] = v.w;
        }
        if (t < 36) {
            int c = t / 9, k = t % 9;
            wbuf[t] = W1[((size_t)(co0 + c) * 512 + ci) * 9 + k];
        }
        __syncthreads();
        float patch[6][6];
#pragma unroll
        for (int dy = 0; dy < 6; ++dy)
#pragma unroll
            for (int dx = 0; dx < 6; ++dx)
                patch[dy][dx] = plane[(y0 + dy) * 67 + (x0 + dx)];
#pragma unroll
        for (int c = 0; c < 4; ++c)
#pragma unroll
            for (int ky = 0; ky < 3; ++ky)
#pragma unroll
                for (int kx = 0; kx < 3; ++kx) {
                    float w = wbuf[c * 9 + ky * 3 + kx];
#pragma unroll
                    for (int qy = 0; qy < 4; ++qy)
#pragma unroll
                        for (int qx = 0; qx < 4; ++qx)
                            acc[c][qy * 4 + qx] = fmaf(patch[qy + ky][qx + kx], w, acc[c][qy * 4 + qx]);
                }
    }
    // fused instance norm + relu (bias cancels in mean subtraction)
    for (int c = 0; c < 4; ++c) {
        float s = 0.f, s2 = 0.f;
#pragma unroll
        for (int q = 0; q < 16; ++q) { float v = acc[c][q]; s += v; s2 = fmaf(v, v, s2); }
        __syncthreads();
        red[t] = s; red2[t] = s2;
        __syncthreads();
        for (int off = 128; off > 0; off >>= 1) {
            if (t < off) { red[t] += red[t + off]; red2[t] += red2[t + off]; }
            __syncthreads();
        }
        if (t == 0) {
            float mean = red[0] * (1.f / 4096.f);
            float var = red2[0] * (1.f / 4096.f) - mean * mean;
            bc[0] = mean; bc[1] = 1.f / sqrtf(var + 1e-5f);
        }
        __syncthreads();
        float mean = bc[0], sc = bc[1];
        float* dst = h + ((size_t)(b * 256 + co0 + c)) * L;
#pragma unroll
        for (int qy = 0; qy < 4; ++qy) {
            float4 v;
            float z0 = (acc[c][qy * 4 + 0] - mean) * sc;
            float z1 = (acc[c][qy * 4 + 1] - mean) * sc;
            float z2 = (acc[c][qy * 4 + 2] - mean) * sc;
            float z3 = (acc[c][qy * 4 + 3] - mean) * sc;
            v.x = z0 > 0.f ? z0 : 0.f;
            v.y = z1 > 0.f ? z1 : 0.f;
            v.z = z2 > 0.f ? z2 : 0.f;
            v.w = z3 > 0.f ? z3 : 0.f;
            *reinterpret_cast<float4*>(dst + (y0 + qy) * 64 + x0) = v;
        }
    }
}

// ---------------- Kernel 6: conv2 (256->256) + instance norm + residual add ----------------
__global__ __launch_bounds__(256) void conv2_inorm_add(
    const float* __restrict__ h, const float* __restrict__ input,
    const float* __restrict__ W2, float* __restrict__ out)
{
    int b = blockIdx.y;
    int co0 = blockIdx.x * 4;
    __shared__ float plane[66 * 67];
    __shared__ float wbuf[36];
    __shared__ float red[256];
    __shared__ float red2[256];
    __shared__ float bc[2];
    int t = threadIdx.x;
    int tx = t & 15, ty = t >> 4;
    int x0 = tx * 4, y0 = ty * 4;
    float acc[4][16];
#pragma unroll
    for (int c = 0; c < 4; ++c)
#pragma unroll
        for (int q = 0; q < 16; ++q) acc[c][q] = 0.f;
    for (int i = t; i < 66 * 67; i += 256) plane[i] = 0.f;
    for (int ci = 0; ci < 256; ++ci) {
        const float* src = h + ((size_t)(b * 256 + ci)) * L;
        __syncthreads();
#pragma unroll
        for (int rep = 0; rep < 4; ++rep) {
            int idx = rep * 256 + t;
            int y = idx >> 4, x4 = idx & 15;
            float4 v = *reinterpret_cast<const float4*>(src + y * 64 + x4 * 4);
            float* dst = &plane[(y + 1) * 67 + 1 + x4 * 4];
            dst[0] = v.x; dst[1] = v.y; dst[2] = v.z; dst[3] = v.w;
        }
        if (t < 36) {
            int c = t / 9, k = t % 9;
            wbuf[t] = W2[((size_t)(co0 + c) * 256 + ci) * 9 + k];
        }
        __syncthreads();
        float patch[6][6];
#pragma unroll
        for (int dy = 0; dy < 6; ++dy)
#pragma unroll
            for (int dx = 0; dx < 6; ++dx)
                patch[dy][dx] = plane[(y0 + dy) * 67 + (x0 + dx)];
#pragma unroll
        for (int c = 0; c < 4; ++c)
#pragma unroll
            for (int ky = 0; ky < 3; ++ky)
#pragma unroll
                for (int kx = 0; kx < 3; ++kx) {
                    float w = wbuf[c * 9 + ky * 3 + kx];
#pragma unroll
                    for (int qy = 0; qy < 4; ++qy)
#pragma unroll
                        for (int qx = 0; qx < 4; ++qx)
                            acc[c][qy * 4 + qx] = fmaf(patch[qy + ky][qx + kx], w, acc[c][qy * 4 + qx]);
                }
    }
    for (int c = 0; c < 4; ++c) {
        float s = 0.f, s2 = 0.f;
#pragma unroll
        for (int q = 0; q < 16; ++q) { float v = acc[c][q]; s += v; s2 = fmaf(v, v, s2); }
        __syncthreads();
        red[t] = s; red2[t] = s2;
        __syncthreads();
        for (int off = 128; off > 0; off >>= 1) {
            if (t < off) { red[t] += red[t + off]; red2[t] += red2[t + off]; }
            __syncthreads();
        }
        if (t == 0) {
            float mean = red[0] * (1.f / 4096.f);
            float var = red2[0] * (1.f / 4096.f) - mean * mean;
            bc[0] = mean; bc[1] = 1.f / sqrtf(var + 1e-5f);
        }
        __syncthreads();
        float mean = bc[0], sc = bc[1];
        const float* fc = input + ((size_t)(b * 512 + co0 + c)) * L;
        float* dst = out + ((size_t)(b * 512 + co0 + c)) * L;
#pragma unroll
        for (int qy = 0; qy < 4; ++qy) {
            float4 f = *reinterpret_cast<const float4*>(fc + (y0 + qy) * 64 + x0);
            float4 v;
            v.x = f.x + (acc[c][qy * 4 + 0] - mean) * sc;
            v.y = f.y + (acc[c][qy * 4 + 1] - mean) * sc;
            v.z = f.z + (acc[c][qy * 4 + 2] - mean) * sc;
            v.w = f.w + (acc[c][qy * 4 + 3] - mean) * sc;
            *reinterpret_cast<float4*>(dst + (y0 + qy) * 64 + x0) = v;
        }
    }
}

// ---------------- Kernel 7: copy F_s to second half of out ----------------
__global__ __launch_bounds__(256) void copy_fs(
    const float* __restrict__ input, float* __restrict__ out)
{
    size_t i = (size_t)blockIdx.x * 256 + threadIdx.x;  // float4 index, 2,097,152 total
    size_t b = i >> 18;            // 262144 float4 per batch half
    size_t r = i & 262143;
    size_t o = ((size_t)(b * 512 + 256)) * 1024 + r;    // in float4 units
    const float4* s = (const float4*)input;
    float4* d = (float4*)out;
    d[o] = s[o];
}

extern "C" void kernel_launch(void* const* d_in, const int* in_sizes, int n_in,
                              void* d_out, int out_size, void* d_ws, size_t ws_size,
                              hipStream_t stream) {
    const float* input = (const float*)d_in[0];
    const int*   mask  = (const int*)d_in[1];
    const float* W1    = (const float*)d_in[2];
    const float* W2    = (const float*)d_in[4];
    float* out = (float*)d_out;
    (void)in_sizes; (void)n_in; (void)out_size;

    const size_t MB32 = (size_t)32 * 1024 * 1024;
    char* ws = (char*)d_ws;
    float *fsn, *fusebuf, *h;
    char* small;
    if (ws_size >= 2 * MB32 + (1 << 21)) {
        fsn = (float*)ws;
        fusebuf = (float*)(ws + MB32);
        small = ws + 2 * MB32;
        h = fsn;                      // fsn dead after sim_argmax
    } else {
        fsn = out;                    // out[0:32MB] scratch until conv2 writes it
        h = out + 8388608;            // out[32:64MB] scratch until copy_fs
        fusebuf = (float*)ws;
        small = ws + MB32;
    }
    int* counts     = (int*)small;                 // 2 (padded to 4)
    int* maskedOrig = counts + 4;                  // 4096
    int* unmaskOrig = maskedOrig + L;              // 4096
    int* posOf      = unmaskOrig + L;              // 4096
    int* idxmap     = posOf + L;                   // B*L

    compact_mask<<<1, 256, 0, stream>>>(mask, counts, maskedOrig, unmaskOrig, posOf);
    norm_transpose<<<1024, 256, 0, stream>>>(input, mask, counts, posOf, fsn);
    sim_argmax<<<dim3(64, 8), 256, 0, stream>>>(fsn, counts, maskedOrig, unmaskOrig, idxmap);
    fuse_kernel<<<32768, 256, 0, stream>>>(input, mask, idxmap, fusebuf);
    conv1_inorm_relu<<<dim3(64, 8), 256, 0, stream>>>(input, fusebuf, W1, h);
    conv2_inorm_add<<<dim3(64, 8), 256, 0, stream>>>(h, input, W2, out);
    copy_fs<<<8192, 256, 0, stream>>>(input, out);
}

// Round 4
// 2758.277 us; speedup vs baseline: 1.3319x; 1.3319x over previous
//
#include <hip/hip_runtime.h>
#include <hip/hip_bf16.h>
#include <math.h>

#define L 4096
#define C 256
#define B 8

typedef __attribute__((ext_vector_type(8))) short bf16x8;
typedef __attribute__((ext_vector_type(4))) float f32x4;

// ---------------- Kernel 1: mask compaction (single block) ----------------
__global__ __launch_bounds__(256) void compact_mask(
    const int* __restrict__ mask, int* __restrict__ counts,
    int* __restrict__ maskedOrig, int* __restrict__ unmaskOrig,
    int* __restrict__ posOf)
{
    __shared__ int smM[256], smU[256];
    int t = threadIdx.x;
    int flags[16];
    int cm = 0, cu = 0;
    for (int k = 0; k < 16; ++k) {
        int l = t * 16 + k;
        int f = mask[l] > 0;
        flags[k] = f;
        cm += f; cu += !f;
    }
    smM[t] = cm; smU[t] = cu;
    __syncthreads();
    for (int off = 1; off < 256; off <<= 1) {
        int vM = 0, vU = 0;
        if (t >= off) { vM = smM[t - off]; vU = smU[t - off]; }
        __syncthreads();
        smM[t] += vM; smU[t] += vU;
        __syncthreads();
    }
    if (t == 255) { counts[0] = smM[255]; counts[1] = smU[255]; }
    int pm = smM[t] - cm, pu = smU[t] - cu;
    for (int k = 0; k < 16; ++k) {
        int l = t * 16 + k;
        if (flags[k]) { maskedOrig[pm] = l; posOf[l] = pm; pm++; }
        else          { unmaskOrig[pu] = l; posOf[l] = pu; pu++; }
    }
}

// ---------------- Kernel 2: normalize rows of F_s -> compacted bf16 hi/lo ----------------
// rows [0..Nm) = masked pixels (ascending l), [Nm..L) = unmasked (ascending l).
__global__ __launch_bounds__(256) void norm_transpose(
    const float* __restrict__ input, const int* __restrict__ mask,
    const int* __restrict__ counts, const int* __restrict__ posOf,
    __hip_bfloat16* __restrict__ fsnh, __hip_bfloat16* __restrict__ fsnl)
{
    int bx = blockIdx.x;           // 0..1023
    int b = bx >> 7;
    int l0 = (bx & 127) * 32;
    __shared__ float tile[256 * 33];
    __shared__ float part[8 * 33];
    __shared__ float denom[32];
    __shared__ int   rowdst[32];
    int t = threadIdx.x;
    int lsub = t & 31, cg = t >> 5;     // cg 0..7
    for (int cc = 0; cc < 256; cc += 8) {
        int c = cc + cg;
        tile[c * 33 + lsub] = input[((size_t)(b * 512 + 256 + c)) * L + l0 + lsub];
    }
    __syncthreads();
    float s = 0.f;
    for (int c = cg; c < 256; c += 8) { float v = tile[c * 33 + lsub]; s = fmaf(v, v, s); }
    part[cg * 33 + lsub] = s;
    __syncthreads();
    if (t < 32) {
        float s2 = 0.f;
        for (int g = 0; g < 8; ++g) s2 += part[g * 33 + t];
        denom[t] = sqrtf(s2) + 1e-8f;
        int l = l0 + t;
        int Nm = counts[0];
        rowdst[t] = (mask[l] > 0) ? posOf[l] : (Nm + posOf[l]);
    }
    __syncthreads();
    for (int ls = 0; ls < 32; ++ls) {
        int r = rowdst[ls];
        float d = denom[ls];
        float val = tile[t * 33 + ls] / d;
        __hip_bfloat16 h = __float2bfloat16(val);
        float hf = __bfloat162float(h);
        __hip_bfloat16 lo = __float2bfloat16(val - hf);
        size_t o = ((size_t)b * L + r) * C + t;
        fsnh[o] = h;
        fsnl[o] = lo;
    }
}

// ---------------- Kernel 3: sim GEMM via MFMA (split-bf16) + per-chunk argmax ----------------
// Block: 64 m x 128 n, 4 waves (wave w = rows m0+w*16..+15), 8 n-frags of 16.
// D layout (m89-verified): col = lane&15 (n), row = (lane>>4)*4 + reg (m).
__global__ __launch_bounds__(256) void sim_argmax_mfma(
    const __hip_bfloat16* __restrict__ hi, const __hip_bfloat16* __restrict__ lo,
    const int* __restrict__ counts,
    float* __restrict__ pval, int* __restrict__ pidx)
{
    int b = blockIdx.z;
    int m0 = blockIdx.y * 64;
    int n0 = blockIdx.x * 128;
    int Nm = counts[0], Nu = counts[1];
    if (m0 >= Nm || n0 >= Nu) return;
    int t = threadIdx.x;
    int w = t >> 6, l = t & 63;
    int lm = l & 15, lk = l >> 4;          // k offset group: lk*8
    const ushort* baseH = (const ushort*)hi + (size_t)b * L * C;
    const ushort* baseL = (const ushort*)lo + (size_t)b * L * C;
    int rA = m0 + w * 16 + lm;             // always < 4096
    const ushort* aHp = baseH + (size_t)rA * C + lk * 8;
    const ushort* aLp = baseL + (size_t)rA * C + lk * 8;
    const ushort* bHp[8]; const ushort* bLp[8];
    int ncol = n0 + lm;
#pragma unroll
    for (int f = 0; f < 8; ++f) {
        int n = ncol + f * 16;
        int rB = (n < Nu) ? (Nm + n) : 0;  // clamp OOB lanes to a valid row
        bHp[f] = baseH + (size_t)rB * C + lk * 8;
        bLp[f] = baseL + (size_t)rB * C + lk * 8;
    }
    f32x4 acc[8];
#pragma unroll
    for (int f = 0; f < 8; ++f) acc[f] = (f32x4){0.f, 0.f, 0.f, 0.f};
    for (int k0 = 0; k0 < C; k0 += 32) {
        bf16x8 ah = *(const bf16x8*)(aHp + k0);
        bf16x8 al = *(const bf16x8*)(aLp + k0);
#pragma unroll
        for (int f = 0; f < 8; ++f) {
            bf16x8 bh = *(const bf16x8*)(bHp[f] + k0);
            bf16x8 bl = *(const bf16x8*)(bLp[f] + k0);
            acc[f] = __builtin_amdgcn_mfma_f32_16x16x32_bf16(ah, bh, acc[f], 0, 0, 0);
            acc[f] = __builtin_amdgcn_mfma_f32_16x16x32_bf16(ah, bl, acc[f], 0, 0, 0);
            acc[f] = __builtin_amdgcn_mfma_f32_16x16x32_bf16(al, bh, acc[f], 0, 0, 0);
        }
    }
    // per-row argmax over this n-chunk; ascending-n scan, strict > => first-max kept
#pragma unroll
    for (int r = 0; r < 4; ++r) {
        float bv = -3e38f; int bn = 0;
#pragma unroll
        for (int f = 0; f < 8; ++f) {
            int n = ncol + f * 16;
            float v = acc[f][r];
            if (n < Nu && v > bv) { bv = v; bn = n; }
        }
#pragma unroll
        for (int mask_ = 1; mask_ < 16; mask_ <<= 1) {
            float ov = __shfl_xor(bv, mask_, 64);
            int   on = __shfl_xor(bn, mask_, 64);
            if (ov > bv || (ov == bv && on < bn)) { bv = ov; bn = on; }
        }
        if (lm == 0) {
            int m = m0 + w * 16 + lk * 4 + r;
            size_t o = (((size_t)(b * 4096 + m)) << 5) + blockIdx.x;
            pval[o] = bv; pidx[o] = bn;
        }
    }
}

// ---------------- Kernel 3b: combine per-chunk argmax partials ----------------
__global__ __launch_bounds__(256) void argmax_reduce(
    const float* __restrict__ pval, const int* __restrict__ pidx,
    const int* __restrict__ counts, const int* __restrict__ maskedOrig,
    const int* __restrict__ unmaskOrig, int* __restrict__ idxmap)
{
    int i = blockIdx.x * 256 + threadIdx.x;   // b*4096 + m
    int b = i >> 12, m = i & 4095;
    int Nm = counts[0], Nu = counts[1];
    if (m >= Nm) return;
    int nch = (Nu + 127) >> 7;
    size_t base = ((size_t)i) << 5;
    float bv = pval[base]; int bn = pidx[base];
    for (int c = 1; c < nch; ++c) {
        float v = pval[base + c];
        if (v > bv) { bv = v; bn = pidx[base + c]; }  // later chunk => larger n; strict >
    }
    idxmap[(b << 12) + maskedOrig[m]] = unmaskOrig[bn];
}

// ---------------- Kernel 5: conv1 (512->256, fuse computed on the fly) + inorm + relu ----------------
__global__ __launch_bounds__(256) void conv1_inorm_relu(
    const float* __restrict__ input, const int* __restrict__ mask,
    const int* __restrict__ idxmap, const float* __restrict__ W1,
    float* __restrict__ h, int hstride, int hoff)
{
    int b = blockIdx.y;
    int co0 = blockIdx.x * 4;
    __shared__ float plane[66 * 67];
    __shared__ int   midx[4096];
    __shared__ float wbuf[36];
    __shared__ float red[256];
    __shared__ float red2[256];
    __shared__ float bc[2];
    int t = threadIdx.x;
    int tx = t & 15, ty = t >> 4;
    int x0 = tx * 4, y0 = ty * 4;
    float acc[4][16];
#pragma unroll
    for (int c = 0; c < 4; ++c)
#pragma unroll
        for (int q = 0; q < 16; ++q) acc[c][q] = 0.f;
    for (int i = t; i < 66 * 67; i += 256) plane[i] = 0.f;
    for (int i = t; i < 4096; i += 256)
        midx[i] = (mask[i] > 0) ? idxmap[(b << 12) + i] : -1;
    for (int ci = 0; ci < 512; ++ci) {
        const float* src = input + ((size_t)(b * 512 + (ci & 255))) * L;
        __syncthreads();
        if (ci < 256) {
#pragma unroll
            for (int rep = 0; rep < 4; ++rep) {
                int idx = rep * 256 + t;            // float4 units
                int y = idx >> 4, x4 = idx & 15;
                float4 v = *reinterpret_cast<const float4*>(src + y * 64 + x4 * 4);
                float* dst = &plane[(y + 1) * 67 + 1 + x4 * 4];
                dst[0] = v.x; dst[1] = v.y; dst[2] = v.z; dst[3] = v.w;
            }
        } else {
#pragma unroll
            for (int rep = 0; rep < 4; ++rep) {
                int idx = rep * 256 + t;
                int y = idx >> 4, x4 = idx & 15;
                int lb = y * 64 + x4 * 4;
                float4 v = *reinterpret_cast<const float4*>(src + lb);
                int m0_ = midx[lb + 0], m1_ = midx[lb + 1], m2_ = midx[lb + 2], m3_ = midx[lb + 3];
                float* dst = &plane[(y + 1) * 67 + 1 + x4 * 4];
                dst[0] = (m0_ >= 0) ? v.x * src[m0_] : 0.f;
                dst[1] = (m1_ >= 0) ? v.y * src[m1_] : 0.f;
                dst[2] = (m2_ >= 0) ? v.z * src[m2_] : 0.f;
                dst[3] = (m3_ >= 0) ? v.w * src[m3_] : 0.f;
            }
        }
        if (t < 36) {
            int c = t / 9, k = t % 9;
            wbuf[t] = W1[((size_t)(co0 + c) * 512 + ci) * 9 + k];
        }
        __syncthreads();
        float patch[6][6];
#pragma unroll
        for (int dy = 0; dy < 6; ++dy)
#pragma unroll
            for (int dx = 0; dx < 6; ++dx)
                patch[dy][dx] = plane[(y0 + dy) * 67 + (x0 + dx)];
#pragma unroll
        for (int c = 0; c < 4; ++c)
#pragma unroll
            for (int ky = 0; ky < 3; ++ky)
#pragma unroll
                for (int kx = 0; kx < 3; ++kx) {
                    float w = wbuf[c * 9 + ky * 3 + kx];
#pragma unroll
                    for (int qy = 0; qy < 4; ++qy)
#pragma unroll
                        for (int qx = 0; qx < 4; ++qx)
                            acc[c][qy * 4 + qx] = fmaf(patch[qy + ky][qx + kx], w, acc[c][qy * 4 + qx]);
                }
    }
    // fused instance norm + relu (bias cancels in mean subtraction)
    for (int c = 0; c < 4; ++c) {
        float s = 0.f, s2 = 0.f;
#pragma unroll
        for (int q = 0; q < 16; ++q) { float v = acc[c][q]; s += v; s2 = fmaf(v, v, s2); }
        __syncthreads();
        red[t] = s; red2[t] = s2;
        __syncthreads();
        for (int off = 128; off > 0; off >>= 1) {
            if (t < off) { red[t] += red[t + off]; red2[t] += red2[t + off]; }
            __syncthreads();
        }
        if (t == 0) {
            float mean = red[0] * (1.f / 4096.f);
            float var = red2[0] * (1.f / 4096.f) - mean * mean;
            bc[0] = mean; bc[1] = 1.f / sqrtf(var + 1e-5f);
        }
        __syncthreads();
        float mean = bc[0], sc = bc[1];
        float* dst = h + ((size_t)(b * hstride + hoff + co0 + c)) * L;
#pragma unroll
        for (int qy = 0; qy < 4; ++qy) {
            float4 v;
            float z0 = (acc[c][qy * 4 + 0] - mean) * sc;
            float z1 = (acc[c][qy * 4 + 1] - mean) * sc;
            float z2 = (acc[c][qy * 4 + 2] - mean) * sc;
            float z3 = (acc[c][qy * 4 + 3] - mean) * sc;
            v.x = z0 > 0.f ? z0 : 0.f;
            v.y = z1 > 0.f ? z1 : 0.f;
            v.z = z2 > 0.f ? z2 : 0.f;
            v.w = z3 > 0.f ? z3 : 0.f;
            *reinterpret_cast<float4*>(dst + (y0 + qy) * 64 + x0) = v;
        }
    }
}

// ---------------- Kernel 6: conv2 (256->256) + instance norm + residual add ----------------
__global__ __launch_bounds__(256) void conv2_inorm_add(
    const float* __restrict__ h, int hstride, int hoff,
    const float* __restrict__ input,
    const float* __restrict__ W2, float* __restrict__ out)
{
    int b = blockIdx.y;
    int co0 = blockIdx.x * 4;
    __shared__ float plane[66 * 67];
    __shared__ float wbuf[36];
    __shared__ float red[256];
    __shared__ float red2[256];
    __shared__ float bc[2];
    int t = threadIdx.x;
    int tx = t & 15, ty = t >> 4;
    int x0 = tx * 4, y0 = ty * 4;
    float acc[4][16];
#pragma unroll
    for (int c = 0; c < 4; ++c)
#pragma unroll
        for (int q = 0; q < 16; ++q) acc[c][q] = 0.f;
    for (int i = t; i < 66 * 67; i += 256) plane[i] = 0.f;
    for (int ci = 0; ci < 256; ++ci) {
        const float* src = h + ((size_t)(b * hstride + hoff + ci)) * L;
        __syncthreads();
#pragma unroll
        for (int rep = 0; rep < 4; ++rep) {
            int idx = rep * 256 + t;
            int y = idx >> 4, x4 = idx & 15;
            float4 v = *reinterpret_cast<const float4*>(src + y * 64 + x4 * 4);
            float* dst = &plane[(y + 1) * 67 + 1 + x4 * 4];
            dst[0] = v.x; dst[1] = v.y; dst[2] = v.z; dst[3] = v.w;
        }
        if (t < 36) {
            int c = t / 9, k = t % 9;
            wbuf[t] = W2[((size_t)(co0 + c) * 256 + ci) * 9 + k];
        }
        __syncthreads();
        float patch[6][6];
#pragma unroll
        for (int dy = 0; dy < 6; ++dy)
#pragma unroll
            for (int dx = 0; dx < 6; ++dx)
                patch[dy][dx] = plane[(y0 + dy) * 67 + (x0 + dx)];
#pragma unroll
        for (int c = 0; c < 4; ++c)
#pragma unroll
            for (int ky = 0; ky < 3; ++ky)
#pragma unroll
                for (int kx = 0; kx < 3; ++kx) {
                    float w = wbuf[c * 9 + ky * 3 + kx];
#pragma unroll
                    for (int qy = 0; qy < 4; ++qy)
#pragma unroll
                        for (int qx = 0; qx < 4; ++qx)
                            acc[c][qy * 4 + qx] = fmaf(patch[qy + ky][qx + kx], w, acc[c][qy * 4 + qx]);
                }
    }
    for (int c = 0; c < 4; ++c) {
        float s = 0.f, s2 = 0.f;
#pragma unroll
        for (int q = 0; q < 16; ++q) { float v = acc[c][q]; s += v; s2 = fmaf(v, v, s2); }
        __syncthreads();
        red[t] = s; red2[t] = s2;
        __syncthreads();
        for (int off = 128; off > 0; off >>= 1) {
            if (t < off) { red[t] += red[t + off]; red2[t] += red2[t + off]; }
            __syncthreads();
        }
        if (t == 0) {
            float mean = red[0] * (1.f / 4096.f);
            float var = red2[0] * (1.f / 4096.f) - mean * mean;
            bc[0] = mean; bc[1] = 1.f / sqrtf(var + 1e-5f);
        }
        __syncthreads();
        float mean = bc[0], sc = bc[1];
        const float* fc = input + ((size_t)(b * 512 + co0 + c)) * L;
        float* dst = out + ((size_t)(b * 512 + co0 + c)) * L;
#pragma unroll
        for (int qy = 0; qy < 4; ++qy) {
            float4 f = *reinterpret_cast<const float4*>(fc + (y0 + qy) * 64 + x0);
            float4 v;
            v.x = f.x + (acc[c][qy * 4 + 0] - mean) * sc;
            v.y = f.y + (acc[c][qy * 4 + 1] - mean) * sc;
            v.z = f.z + (acc[c][qy * 4 + 2] - mean) * sc;
            v.w = f.w + (acc[c][qy * 4 + 3] - mean) * sc;
            *reinterpret_cast<float4*>(dst + (y0 + qy) * 64 + x0) = v;
        }
    }
}

// ---------------- Kernel 7: copy F_s to second half of out ----------------
__global__ __launch_bounds__(256) void copy_fs(
    const float* __restrict__ input, float* __restrict__ out)
{
    size_t i = (size_t)blockIdx.x * 256 + threadIdx.x;  // float4 index
    size_t b = i >> 18;
    size_t r = i & 262143;
    size_t o = ((size_t)(b * 512 + 256)) * 1024 + r;
    const float4* s = (const float4*)input;
    float4* d = (float4*)out;
    d[o] = s[o];
}

extern "C" void kernel_launch(void* const* d_in, const int* in_sizes, int n_in,
                              void* d_out, int out_size, void* d_ws, size_t ws_size,
                              hipStream_t stream) {
    const float* input = (const float*)d_in[0];
    const int*   mask  = (const int*)d_in[1];
    const float* W1    = (const float*)d_in[2];
    const float* W2    = (const float*)d_in[4];
    float* out = (float*)d_out;
    (void)in_sizes; (void)n_in; (void)out_size;

    const size_t MB = (size_t)1024 * 1024;
    char* ws = (char*)d_ws;

    __hip_bfloat16 *fsnh, *fsnl;
    float* pval; int* pidx;
    char* small;
    float* h; int hstride, hoff;

    if (ws_size >= 42 * MB) {
        // Plan A: everything in ws; h reuses the (dead after sim) fsn region.
        fsnh = (__hip_bfloat16*)ws;                 // 16 MB
        fsnl = (__hip_bfloat16*)(ws + 16 * MB);     // 16 MB
        pval = (float*)(ws + 32 * MB);              // 4 MB
        pidx = (int*)(ws + 36 * MB);                // 4 MB
        small = ws + 40 * MB;
        h = (float*)ws; hstride = 256; hoff = 0;    // 32 MB over dead fsn
    } else {
        // Plan B: stage in out; h lives scattered in out's F_s half (overwritten by copy_fs last).
        fsnh = (__hip_bfloat16*)out;                        // out[0:16MB]
        fsnl = (__hip_bfloat16*)((char*)out + 16 * MB);     // out[16:32MB]
        pval = (float*)((char*)out + 32 * MB);              // out[32:36MB]
        pidx = (int*)((char*)out + 36 * MB);                // out[36:40MB]
        small = ws;
        h = out; hstride = 512; hoff = 256;
    }
    int* counts     = (int*)small;                 // 4
    int* maskedOrig = counts + 4;                  // 4096
    int* unmaskOrig = maskedOrig + L;              // 4096
    int* posOf      = unmaskOrig + L;              // 4096
    int* idxmap     = posOf + L;                   // B*L

    compact_mask<<<1, 256, 0, stream>>>(mask, counts, maskedOrig, unmaskOrig, posOf);
    norm_transpose<<<1024, 256, 0, stream>>>(input, mask, counts, posOf, fsnh, fsnl);
    sim_argmax_mfma<<<dim3(32, 64, 8), 256, 0, stream>>>(fsnh, fsnl, counts, pval, pidx);
    argmax_reduce<<<128, 256, 0, stream>>>(pval, pidx, counts, maskedOrig, unmaskOrig, idxmap);
    conv1_inorm_relu<<<dim3(64, 8), 256, 0, stream>>>(input, mask, idxmap, W1, h, hstride, hoff);
    conv2_inorm_add<<<dim3(64, 8), 256, 0, stream>>>(h, hstride, hoff, input, W2, out);
    copy_fs<<<8192, 256, 0, stream>>>(input, out);
}

// Round 5
// 749.236 us; speedup vs baseline: 4.9035x; 3.6815x over previous
//
#include <hip/hip_runtime.h>
#include <hip/hip_bf16.h>
#include <math.h>

#define L 4096
#define C 256
#define B 8

typedef __attribute__((ext_vector_type(8))) short bf16x8;
typedef __attribute__((ext_vector_type(8))) ushort u16x8;
typedef __attribute__((ext_vector_type(4))) float f32x4;

__device__ inline ushort f2bu(float f) { __hip_bfloat16 h = __float2bfloat16(f); return *(ushort*)&h; }
__device__ inline float bu2f(ushort u) { __hip_bfloat16 h; *(ushort*)&h = u; return __bfloat162float(h); }

// ---------------- Kernel 1: mask compaction (single block) ----------------
__global__ __launch_bounds__(256) void compact_mask(
    const int* __restrict__ mask, int* __restrict__ counts,
    int* __restrict__ maskedOrig, int* __restrict__ unmaskOrig,
    int* __restrict__ posOf)
{
    __shared__ int smM[256], smU[256];
    int t = threadIdx.x;
    int flags[16];
    int cm = 0, cu = 0;
    for (int k = 0; k < 16; ++k) {
        int l = t * 16 + k;
        int f = mask[l] > 0;
        flags[k] = f;
        cm += f; cu += !f;
    }
    smM[t] = cm; smU[t] = cu;
    __syncthreads();
    for (int off = 1; off < 256; off <<= 1) {
        int vM = 0, vU = 0;
        if (t >= off) { vM = smM[t - off]; vU = smU[t - off]; }
        __syncthreads();
        smM[t] += vM; smU[t] += vU;
        __syncthreads();
    }
    if (t == 255) { counts[0] = smM[255]; counts[1] = smU[255]; }
    int pm = smM[t] - cm, pu = smU[t] - cu;
    for (int k = 0; k < 16; ++k) {
        int l = t * 16 + k;
        if (flags[k]) { maskedOrig[pm] = l; posOf[l] = pm; pm++; }
        else          { unmaskOrig[pu] = l; posOf[l] = pu; pu++; }
    }
}

// ---------------- Kernel 2: normalize rows of F_s -> compacted bf16 hi/lo ----------------
__global__ __launch_bounds__(256) void norm_transpose(
    const float* __restrict__ input, const int* __restrict__ mask,
    const int* __restrict__ counts, const int* __restrict__ posOf,
    ushort* __restrict__ fsnh, ushort* __restrict__ fsnl)
{
    int bx = blockIdx.x;           // 0..1023
    int b = bx >> 7;
    int l0 = (bx & 127) * 32;
    __shared__ float tile[256 * 33];
    __shared__ float part[8 * 33];
    __shared__ float denom[32];
    __shared__ int   rowdst[32];
    int t = threadIdx.x;
    int lsub = t & 31, cg = t >> 5;
    for (int cc = 0; cc < 256; cc += 8) {
        int c = cc + cg;
        tile[c * 33 + lsub] = input[((size_t)(b * 512 + 256 + c)) * L + l0 + lsub];
    }
    __syncthreads();
    float s = 0.f;
    for (int c = cg; c < 256; c += 8) { float v = tile[c * 33 + lsub]; s = fmaf(v, v, s); }
    part[cg * 33 + lsub] = s;
    __syncthreads();
    if (t < 32) {
        float s2 = 0.f;
        for (int g = 0; g < 8; ++g) s2 += part[g * 33 + t];
        denom[t] = sqrtf(s2) + 1e-8f;
        int l = l0 + t;
        int Nm = counts[0];
        rowdst[t] = (mask[l] > 0) ? posOf[l] : (Nm + posOf[l]);
    }
    __syncthreads();
    for (int ls = 0; ls < 32; ++ls) {
        int r = rowdst[ls];
        float d = denom[ls];
        float val = tile[t * 33 + ls] / d;
        ushort h = f2bu(val);
        float hf = bu2f(h);
        ushort lo = f2bu(val - hf);
        size_t o = ((size_t)b * L + r) * C + t;
        fsnh[o] = h;
        fsnl[o] = lo;
    }
}

// ---------------- Kernel 3: sim GEMM via MFMA (split-bf16) + per-chunk argmax ----------------
__global__ __launch_bounds__(256) void sim_argmax_mfma(
    const ushort* __restrict__ hi, const ushort* __restrict__ lo,
    const int* __restrict__ counts,
    float* __restrict__ pval, int* __restrict__ pidx)
{
    int b = blockIdx.z;
    int m0 = blockIdx.y * 64;
    int n0 = blockIdx.x * 128;
    int Nm = counts[0], Nu = counts[1];
    if (m0 >= Nm || n0 >= Nu) return;
    int t = threadIdx.x;
    int w = t >> 6, l = t & 63;
    int lm = l & 15, lk = l >> 4;
    const ushort* baseH = hi + (size_t)b * L * C;
    const ushort* baseL = lo + (size_t)b * L * C;
    int rA = m0 + w * 16 + lm;
    const ushort* aHp = baseH + (size_t)rA * C + lk * 8;
    const ushort* aLp = baseL + (size_t)rA * C + lk * 8;
    const ushort* bHp[8]; const ushort* bLp[8];
    int ncol = n0 + lm;
#pragma unroll
    for (int f = 0; f < 8; ++f) {
        int n = ncol + f * 16;
        int rB = (n < Nu) ? (Nm + n) : 0;
        bHp[f] = baseH + (size_t)rB * C + lk * 8;
        bLp[f] = baseL + (size_t)rB * C + lk * 8;
    }
    f32x4 acc[8];
#pragma unroll
    for (int f = 0; f < 8; ++f) acc[f] = (f32x4){0.f, 0.f, 0.f, 0.f};
    for (int k0 = 0; k0 < C; k0 += 32) {
        bf16x8 ah = *(const bf16x8*)(aHp + k0);
        bf16x8 al = *(const bf16x8*)(aLp + k0);
#pragma unroll
        for (int f = 0; f < 8; ++f) {
            bf16x8 bh = *(const bf16x8*)(bHp[f] + k0);
            bf16x8 bl = *(const bf16x8*)(bLp[f] + k0);
            acc[f] = __builtin_amdgcn_mfma_f32_16x16x32_bf16(ah, bh, acc[f], 0, 0, 0);
            acc[f] = __builtin_amdgcn_mfma_f32_16x16x32_bf16(ah, bl, acc[f], 0, 0, 0);
            acc[f] = __builtin_amdgcn_mfma_f32_16x16x32_bf16(al, bh, acc[f], 0, 0, 0);
        }
    }
#pragma unroll
    for (int r = 0; r < 4; ++r) {
        float bv = -3e38f; int bn = 0;
#pragma unroll
        for (int f = 0; f < 8; ++f) {
            int n = ncol + f * 16;
            float v = acc[f][r];
            if (n < Nu && v > bv) { bv = v; bn = n; }
        }
#pragma unroll
        for (int mask_ = 1; mask_ < 16; mask_ <<= 1) {
            float ov = __shfl_xor(bv, mask_, 64);
            int   on = __shfl_xor(bn, mask_, 64);
            if (ov > bv || (ov == bv && on < bn)) { bv = ov; bn = on; }
        }
        if (lm == 0) {
            int m = m0 + w * 16 + lk * 4 + r;
            size_t o = (((size_t)(b * 4096 + m)) << 5) + blockIdx.x;
            pval[o] = bv; pidx[o] = bn;
        }
    }
}

// ---------------- Kernel 3b: combine per-chunk argmax partials ----------------
__global__ __launch_bounds__(256) void argmax_reduce(
    const float* __restrict__ pval, const int* __restrict__ pidx,
    const int* __restrict__ counts, const int* __restrict__ maskedOrig,
    const int* __restrict__ unmaskOrig, int* __restrict__ idxmap)
{
    int i = blockIdx.x * 256 + threadIdx.x;
    int b = i >> 12, m = i & 4095;
    int Nm = counts[0], Nu = counts[1];
    if (m >= Nm) return;
    int nch = (Nu + 127) >> 7;
    size_t base = ((size_t)i) << 5;
    float bv = pval[base]; int bn = pidx[base];
    for (int c = 1; c < nch; ++c) {
        float v = pval[base + c];
        if (v > bv) { bv = v; bn = pidx[base + c]; }
    }
    idxmap[(b << 12) + maskedOrig[m]] = unmaskOrig[bn];
}

// ---------------- Kernel 4: weight prep fp32 [co][ci][tau] -> bf16 [co][tau][ci] ----------------
__global__ __launch_bounds__(256) void wprep(
    const float* __restrict__ W1, const float* __restrict__ W2,
    ushort* __restrict__ W1bf, ushort* __restrict__ W2bf)
{
    int gid = blockIdx.x * 256 + threadIdx.x;
    const int N1 = 256 * 512 * 9;
    const int N2 = 256 * 256 * 9;
    if (gid < N1) {
        int ci = gid & 511; int rest = gid >> 9;
        int tau = rest % 9; int co = rest / 9;
        W1bf[gid] = f2bu(W1[((size_t)(co * 512 + ci)) * 9 + tau]);
    } else if (gid < N1 + N2) {
        int g = gid - N1;
        int ci = g & 255; int rest = g >> 8;
        int tau = rest % 9; int co = rest / 9;
        W2bf[g] = f2bu(W2[((size_t)(co * 256 + ci)) * 9 + tau]);
    }
}

// ---------------- Kernel 5: transpose F_c -> inT[b][pix][0:256] bf16 (rows of 512) ----------------
__global__ __launch_bounds__(256) void in_prep1(
    const float* __restrict__ input, ushort* __restrict__ inT)
{
    int b = blockIdx.y;
    int p0 = blockIdx.x * 32;
    __shared__ float tile[256][33];
    int t = threadIdx.x;
    int pq = t & 7;
    for (int cc = 0; cc < 256; cc += 32) {
        int ci = cc + (t >> 3);
        float4 v = *(const float4*)(input + ((size_t)(b * 512 + ci)) * L + p0 + pq * 4);
        tile[ci][pq * 4 + 0] = v.x; tile[ci][pq * 4 + 1] = v.y;
        tile[ci][pq * 4 + 2] = v.z; tile[ci][pq * 4 + 3] = v.w;
    }
    __syncthreads();
    int c8 = t & 31;
    for (int pp = 0; pp < 32; pp += 8) {
        int pixloc = pp + (t >> 5);
        u16x8 u;
#pragma unroll
        for (int j = 0; j < 8; ++j) u[j] = f2bu(tile[c8 * 8 + j][pixloc]);
        *(u16x8*)(inT + ((size_t)(b * 4096 + p0 + pixloc)) * 512 + c8 * 8) = u;
    }
}

// ---------------- Kernel 6: fuse fill inT[b][pix][256:512] = row(p) * row(idx[p]) ----------------
__global__ __launch_bounds__(256) void in_prep2(
    ushort* __restrict__ inT, const int* __restrict__ mask,
    const int* __restrict__ idxmap)
{
    int gid = blockIdx.x * 256 + threadIdx.x;   // 1,048,576 total
    int c8 = gid & 31;
    int pix = (gid >> 5) & 4095;
    int b = gid >> 17;
    u16x8 out8;
    if (mask[pix] > 0) {
        int n = idxmap[(b << 12) + pix];
        const ushort* rp = inT + ((size_t)(b * 4096 + pix)) * 512 + c8 * 8;
        const ushort* rn = inT + ((size_t)(b * 4096 + n)) * 512 + c8 * 8;
        u16x8 a = *(const u16x8*)rp;
        u16x8 bb = *(const u16x8*)rn;
#pragma unroll
        for (int j = 0; j < 8; ++j) out8[j] = f2bu(bu2f(a[j]) * bu2f(bb[j]));
    } else {
#pragma unroll
        for (int j = 0; j < 8; ++j) out8[j] = 0;
    }
    *(u16x8*)(inT + ((size_t)(b * 4096 + pix)) * 512 + 256 + c8 * 8) = out8;
}

// ---------------- Kernel 7: implicit-GEMM 3x3 conv via MFMA ----------------
// Block: 256 px (4 rows) x 64 couts, 4 waves (wave w = image row y0+w, 4x4 frags).
// A-tile LDS: [6 rows][66 cX][32 ci] bf16, XOR-swizzled (2-bit key on cX).
// B-tile LDS: [9 tap][64 cl][32 ci] bf16, swizzled on cl.
template<int CKROW>
__global__ __launch_bounds__(256, 2) void conv_mfma(
    const ushort* __restrict__ Abf, const ushort* __restrict__ Wbf,
    float* __restrict__ outF, ushort* __restrict__ outH,
    float* __restrict__ psum, int store32)
{
    __shared__ float4 ldsv[62208 / 16];
    char* lds = (char*)ldsv;
    char* ldsB = lds + 25344;
    const int t = threadIdx.x;
    const int w = t >> 6;
    const int l = t & 63;
    const int lm = l & 15, lk = l >> 4;
    const int b = blockIdx.z;
    const int y0 = blockIdx.x * 4;
    const int c0 = blockIdx.y * 64;
    const int yw = y0 + w;
    const size_t abase = (size_t)b * 4096 * CKROW;

    f32x4 acc[4][4];
#pragma unroll
    for (int g = 0; g < 4; ++g)
#pragma unroll
        for (int nf = 0; nf < 4; ++nf) acc[g][nf] = (f32x4){0.f, 0.f, 0.f, 0.f};

    // zero halo columns (cX = 0 and 65) once; never overwritten afterwards
    if (t < 48) {
        int r = t >> 3;
        int cX = ((t >> 2) & 1) ? 65 : 0;
        int k8 = t & 3;
        *(float4*)(lds + (r * 66 + cX) * 64 + ((k8 * 16) ^ ((cX & 3) << 4))) = (float4){0.f,0.f,0.f,0.f};
    }

    const int NKC = CKROW / 32;
    for (int kc = 0; kc < NKC; ++kc) {
        __syncthreads();
        // stage A: 6 rows x 64 x x 32 ci
        {
            int x = t >> 2;
            int k8 = t & 3;
            int cX = x + 1;
            char* dbase = lds + cX * 64 + ((k8 * 16) ^ ((cX & 3) << 4));
#pragma unroll
            for (int r = 0; r < 6; ++r) {
                int yy = y0 - 1 + r;
                float4 v;
                if (yy >= 0 && yy < 64)
                    v = *(const float4*)(Abf + abase + (size_t)(yy * 64 + x) * CKROW + kc * 32 + k8 * 8);
                else
                    v = (float4){0.f, 0.f, 0.f, 0.f};
                *(float4*)(dbase + r * (66 * 64)) = v;
            }
        }
        // stage B: 9 taps x 64 cl x 32 ci
        {
            int cl = t >> 2;
            int k8 = t & 3;
            char* dbase = ldsB + cl * 64 + ((k8 * 16) ^ ((cl & 3) << 4));
            const ushort* sbase = Wbf + ((size_t)(c0 + cl) * 9) * CKROW + kc * 32 + k8 * 8;
#pragma unroll
            for (int tau = 0; tau < 9; ++tau) {
                *(float4*)(dbase + tau * (64 * 64)) = *(const float4*)(sbase + (size_t)tau * CKROW);
            }
        }
        __syncthreads();
        // compute: 9 taps x 4x4 frags
#pragma unroll
        for (int ky = 0; ky < 3; ++ky) {
            int r = w + ky;
#pragma unroll
            for (int kx = 0; kx < 3; ++kx) {
                int tau = ky * 3 + kx;
                bf16x8 bfr[4];
#pragma unroll
                for (int nf = 0; nf < 4; ++nf) {
                    int cl = nf * 16 + lm;
                    bfr[nf] = *(bf16x8*)(ldsB + (tau * 64 + cl) * 64 + ((lk * 16) ^ ((cl & 3) << 4)));
                }
#pragma unroll
                for (int g = 0; g < 4; ++g) {
                    int cX = g * 16 + lm + kx;
                    bf16x8 afr = *(bf16x8*)(lds + (r * 66 + cX) * 64 + ((lk * 16) ^ ((cX & 3) << 4)));
#pragma unroll
                    for (int nf = 0; nf < 4; ++nf)
                        acc[g][nf] = __builtin_amdgcn_mfma_f32_16x16x32_bf16(afr, bfr[nf], acc[g][nf], 0, 0, 0);
                }
            }
        }
    }

    // store output: D layout col=lane&15, row=(lane>>4)*4+reg
    if (store32) {
#pragma unroll
        for (int g = 0; g < 4; ++g)
#pragma unroll
            for (int nf = 0; nf < 4; ++nf) {
                int cout = c0 + nf * 16 + lm;
#pragma unroll
                for (int r = 0; r < 4; ++r) {
                    int pix = yw * 64 + g * 16 + lk * 4 + r;
                    outF[((size_t)(b * 4096 + pix)) * 256 + cout] = acc[g][nf][r];
                }
            }
    } else {
#pragma unroll
        for (int g = 0; g < 4; ++g)
#pragma unroll
            for (int nf = 0; nf < 4; ++nf) {
                int cout = c0 + nf * 16 + lm;
#pragma unroll
                for (int r = 0; r < 4; ++r) {
                    int pix = yw * 64 + g * 16 + lk * 4 + r;
                    outH[((size_t)(b * 4096 + pix)) * 256 + cout] = f2bu(acc[g][nf][r]);
                }
            }
    }

    // per-block stats: sum / sumsq per cout over the block's 256 pixels
    float s[4], q[4];
#pragma unroll
    for (int nf = 0; nf < 4; ++nf) {
        float ss = 0.f, qq = 0.f;
#pragma unroll
        for (int g = 0; g < 4; ++g)
#pragma unroll
            for (int r = 0; r < 4; ++r) { float v = acc[g][nf][r]; ss += v; qq = fmaf(v, v, qq); }
        ss += __shfl_xor(ss, 16, 64); ss += __shfl_xor(ss, 32, 64);
        qq += __shfl_xor(qq, 16, 64); qq += __shfl_xor(qq, 32, 64);
        s[nf] = ss; q[nf] = qq;
    }
    __syncthreads();
    float* S = (float*)lds;
    float* Q = (float*)(lds + 1024);
    if (l < 16) {
#pragma unroll
        for (int nf = 0; nf < 4; ++nf) {
            S[w * 64 + nf * 16 + l] = s[nf];
            Q[w * 64 + nf * 16 + l] = q[nf];
        }
    }
    __syncthreads();
    if (t < 64) {
        float ts = 0.f, tq = 0.f;
#pragma unroll
        for (int w2 = 0; w2 < 4; ++w2) { ts += S[w2 * 64 + t]; tq += Q[w2 * 64 + t]; }
        size_t o = (((size_t)(b * 256 + c0 + t)) * 16 + blockIdx.x) * 2;
        psum[o] = ts; psum[o + 1] = tq;
    }
}

// ---------------- Kernel 8: partials -> mean/rstd per (b, cout) ----------------
__global__ __launch_bounds__(256) void stats_reduce(
    const float* __restrict__ psum, float* __restrict__ mrs)
{
    int b = blockIdx.x;
    int c = threadIdx.x;
    float s = 0.f, q = 0.f;
    size_t base = ((size_t)(b * 256 + c)) * 16;
    for (int k = 0; k < 16; ++k) { s += psum[(base + k) * 2]; q += psum[(base + k) * 2 + 1]; }
    float mean = s * (1.f / 4096.f);
    float var = q * (1.f / 4096.f) - mean * mean;
    float rs = rsqrtf(var + 1e-5f);
    mrs[(b * 256 + c) * 2] = mean;
    mrs[(b * 256 + c) * 2 + 1] = rs;
}

// ---------------- Kernel 9: hbf = bf16(relu((h_raw - m) * rs)), pixel-major ----------------
__global__ __launch_bounds__(256) void norm1_apply(
    const float* __restrict__ h_raw, const float* __restrict__ mrs,
    ushort* __restrict__ hbf)
{
    int gid = blockIdx.x * 256 + threadIdx.x;   // 2,097,152 total (float4 units)
    int c4 = gid & 63;
    int pix = (gid >> 6) & 4095;
    int b = gid >> 18;
    float4 hv = *(const float4*)(h_raw + (((size_t)(b * 4096 + pix)) << 8) + c4 * 4);
    const float4* mv = (const float4*)(mrs + (size_t)b * 512);
    float4 m0 = mv[c4 * 2];
    float4 m1 = mv[c4 * 2 + 1];
    float z0 = (hv.x - m0.x) * m0.y;
    float z1 = (hv.y - m0.z) * m0.w;
    float z2 = (hv.z - m1.x) * m1.y;
    float z3 = (hv.w - m1.z) * m1.w;
    ushort4 o;
    o.x = f2bu(z0 > 0.f ? z0 : 0.f);
    o.y = f2bu(z1 > 0.f ? z1 : 0.f);
    o.z = f2bu(z2 > 0.f ? z2 : 0.f);
    o.w = f2bu(z3 > 0.f ? z3 : 0.f);
    *(ushort4*)(hbf + (((size_t)(b * 4096 + pix)) << 8) + c4 * 4) = o;
}

// ---------------- Kernel 10: out F_c-half = F_c + (res - m) * rs (transpose back) ----------------
__global__ __launch_bounds__(256) void finalize(
    const ushort* __restrict__ resbf, const float* __restrict__ mrs,
    const float* __restrict__ input, float* __restrict__ out)
{
    int b = blockIdx.y;
    int p0 = blockIdx.x * 32;
    __shared__ float tileT[256][33];
    int t = threadIdx.x;
    int c8 = t & 31;
    for (int pp = 0; pp < 32; pp += 8) {
        int pixloc = pp + (t >> 5);
        u16x8 u = *(const u16x8*)(resbf + (((size_t)(b * 4096 + p0 + pixloc)) << 8) + c8 * 8);
#pragma unroll
        for (int j = 0; j < 8; ++j) tileT[c8 * 8 + j][pixloc] = bu2f(u[j]);
    }
    __syncthreads();
    int pq = t & 7;
    for (int cc = 0; cc < 256; cc += 32) {
        int c = cc + (t >> 3);
        float m = mrs[(b * 256 + c) * 2];
        float rs = mrs[(b * 256 + c) * 2 + 1];
        size_t off = ((size_t)(b * 512 + c)) * L + p0 + pq * 4;
        float4 f = *(const float4*)(input + off);
        float4 o;
        o.x = f.x + (tileT[c][pq * 4 + 0] - m) * rs;
        o.y = f.y + (tileT[c][pq * 4 + 1] - m) * rs;
        o.z = f.z + (tileT[c][pq * 4 + 2] - m) * rs;
        o.w = f.w + (tileT[c][pq * 4 + 3] - m) * rs;
        *(float4*)(out + off) = o;
    }
}

// ---------------- Kernel 11: copy F_s to second half of out ----------------
__global__ __launch_bounds__(256) void copy_fs(
    const float* __restrict__ input, float* __restrict__ out)
{
    size_t i = (size_t)blockIdx.x * 256 + threadIdx.x;
    size_t b = i >> 18;
    size_t r = i & 262143;
    size_t o = ((size_t)(b * 512 + 256)) * 1024 + r;
    const float4* s = (const float4*)input;
    float4* d = (float4*)out;
    d[o] = s[o];
}

extern "C" void kernel_launch(void* const* d_in, const int* in_sizes, int n_in,
                              void* d_out, int out_size, void* d_ws, size_t ws_size,
                              hipStream_t stream) {
    const float* input = (const float*)d_in[0];
    const int*   mask  = (const int*)d_in[1];
    const float* W1    = (const float*)d_in[2];
    const float* W2    = (const float*)d_in[4];
    float* out = (float*)d_out;
    (void)in_sizes; (void)n_in; (void)out_size; (void)ws_size;

    char* ob = (char*)d_out;
    char* wp = (char*)d_ws;

    // ---- out-region overlays (phase-ordered, no overlap within a phase) ----
    // Phase I (shift):   fsnh[0:16M) fsnl[16:32M) pval[32:36M) pidx[36:40M)
    // Phase II (conv1):  inT[0:32M)  h_raw[32:64M)
    // Phase III (conv2): hbf[0:16M)
    ushort* fsnh = (ushort*)ob;
    ushort* fsnl = (ushort*)(ob + 16777216);
    float*  pval = (float*)(ob + 33554432);
    int*    pidx = (int*)(ob + 37748736);
    ushort* inT  = (ushort*)ob;
    float*  h_raw = (float*)(ob + 33554432);
    ushort* hbf  = (ushort*)ob;

    // ---- ws regions (~21.1 MB) ----
    ushort* resbf  = (ushort*)wp;                        // 16,777,216
    ushort* W1bf   = (ushort*)(wp + 16777216);           //  2,359,296
    ushort* W2bf   = (ushort*)(wp + 19136512);           //  1,179,648
    float*  psum1  = (float*)(wp + 20316160);            //    262,144
    float*  psum2  = (float*)(wp + 20578304);            //    262,144
    float*  mrs1   = (float*)(wp + 20840448);            //     16,384
    float*  mrs2   = (float*)(wp + 20856832);            //     16,384
    int* counts     = (int*)(wp + 20873216);             //         16
    int* maskedOrig = counts + 4;                        //     16,384
    int* unmaskOrig = maskedOrig + L;                    //     16,384
    int* posOf      = unmaskOrig + L;                    //     16,384
    int* idxmap     = posOf + L;                         //    131,072

    compact_mask<<<1, 256, 0, stream>>>(mask, counts, maskedOrig, unmaskOrig, posOf);
    norm_transpose<<<1024, 256, 0, stream>>>(input, mask, counts, posOf, fsnh, fsnl);
    sim_argmax_mfma<<<dim3(32, 64, 8), 256, 0, stream>>>(fsnh, fsnl, counts, pval, pidx);
    argmax_reduce<<<128, 256, 0, stream>>>(pval, pidx, counts, maskedOrig, unmaskOrig, idxmap);
    wprep<<<6912, 256, 0, stream>>>(W1, W2, W1bf, W2bf);
    in_prep1<<<dim3(128, 8), 256, 0, stream>>>(input, inT);
    in_prep2<<<4096, 256, 0, stream>>>(inT, mask, idxmap);
    conv_mfma<512><<<dim3(16, 4, 8), 256, 0, stream>>>(inT, W1bf, h_raw, (ushort*)nullptr, psum1, 1);
    stats_reduce<<<8, 256, 0, stream>>>(psum1, mrs1);
    norm1_apply<<<8192, 256, 0, stream>>>(h_raw, mrs1, hbf);
    conv_mfma<256><<<dim3(16, 4, 8), 256, 0, stream>>>(hbf, W2bf, (float*)nullptr, resbf, psum2, 0);
    stats_reduce<<<8, 256, 0, stream>>>(psum2, mrs2);
    finalize<<<dim3(128, 8), 256, 0, stream>>>(resbf, mrs2, input, out);
    copy_fs<<<8192, 256, 0, stream>>>(input, out);
}

// Round 6
// 282.143 us; speedup vs baseline: 13.0213x; 2.6555x over previous
//
#include <hip/hip_runtime.h>
#include <hip/hip_bf16.h>
#include <math.h>

#define L 4096
#define C 256
#define B 8

typedef __attribute__((ext_vector_type(8))) short bf16x8;
typedef __attribute__((ext_vector_type(8))) ushort u16x8;
typedef __attribute__((ext_vector_type(4))) float f32x4;

__device__ inline ushort f2bu(float f) { __hip_bfloat16 h = __float2bfloat16(f); return *(ushort*)&h; }
__device__ inline float bu2f(ushort u) { __hip_bfloat16 h; *(ushort*)&h = u; return __bfloat162float(h); }

// ---------------- Kernel 1: mask compaction (single block) ----------------
__global__ __launch_bounds__(256) void compact_mask(
    const int* __restrict__ mask, int* __restrict__ counts,
    int* __restrict__ maskedOrig, int* __restrict__ unmaskOrig,
    int* __restrict__ posOf)
{
    __shared__ int smM[256], smU[256];
    int t = threadIdx.x;
    int flags[16];
    int cm = 0, cu = 0;
    for (int k = 0; k < 16; ++k) {
        int l = t * 16 + k;
        int f = mask[l] > 0;
        flags[k] = f;
        cm += f; cu += !f;
    }
    smM[t] = cm; smU[t] = cu;
    __syncthreads();
    for (int off = 1; off < 256; off <<= 1) {
        int vM = 0, vU = 0;
        if (t >= off) { vM = smM[t - off]; vU = smU[t - off]; }
        __syncthreads();
        smM[t] += vM; smU[t] += vU;
        __syncthreads();
    }
    if (t == 255) { counts[0] = smM[255]; counts[1] = smU[255]; }
    int pm = smM[t] - cm, pu = smU[t] - cu;
    for (int k = 0; k < 16; ++k) {
        int l = t * 16 + k;
        if (flags[k]) { maskedOrig[pm] = l; posOf[l] = pm; pm++; }
        else          { unmaskOrig[pu] = l; posOf[l] = pu; pu++; }
    }
}

// ---------------- Kernel 2: normalize rows of F_s -> compacted bf16 hi/lo ----------------
__global__ __launch_bounds__(256) void norm_transpose(
    const float* __restrict__ input, const int* __restrict__ mask,
    const int* __restrict__ counts, const int* __restrict__ posOf,
    ushort* __restrict__ fsnh, ushort* __restrict__ fsnl)
{
    int bx = blockIdx.x;           // 0..1023
    int b = bx >> 7;
    int l0 = (bx & 127) * 32;
    __shared__ float tile[256 * 33];
    __shared__ float part[8 * 33];
    __shared__ float denom[32];
    __shared__ int   rowdst[32];
    int t = threadIdx.x;
    int lsub = t & 31, cg = t >> 5;
    for (int cc = 0; cc < 256; cc += 8) {
        int c = cc + cg;
        tile[c * 33 + lsub] = input[((size_t)(b * 512 + 256 + c)) * L + l0 + lsub];
    }
    __syncthreads();
    float s = 0.f;
    for (int c = cg; c < 256; c += 8) { float v = tile[c * 33 + lsub]; s = fmaf(v, v, s); }
    part[cg * 33 + lsub] = s;
    __syncthreads();
    if (t < 32) {
        float s2 = 0.f;
        for (int g = 0; g < 8; ++g) s2 += part[g * 33 + t];
        denom[t] = sqrtf(s2) + 1e-8f;
        int l = l0 + t;
        int Nm = counts[0];
        rowdst[t] = (mask[l] > 0) ? posOf[l] : (Nm + posOf[l]);
    }
    __syncthreads();
    for (int ls = 0; ls < 32; ++ls) {
        int r = rowdst[ls];
        float d = denom[ls];
        float val = tile[t * 33 + ls] / d;
        ushort h = f2bu(val);
        float hf = bu2f(h);
        ushort lo = f2bu(val - hf);
        size_t o = ((size_t)b * L + r) * C + t;
        fsnh[o] = h;
        fsnl[o] = lo;
    }
}

// ---------------- Kernel 3: sim GEMM, LDS-staged persistent-n + fused argmax ----------------
// Grid (2 halves, 64 m-tiles, 8 b). Block: 64 m x n-sweep, 4 waves.
// A (hi/lo) in registers; B-tile 64 rows x 256 k (hi+lo, 64KB) staged per chunk via
// global_load_lds with pre-swizzled source; reads use byte ^= ((row&7)<<4).
__global__ __launch_bounds__(256, 2) void sim_argmax_v2(
    const ushort* __restrict__ hi, const ushort* __restrict__ lo,
    const int* __restrict__ counts,
    float* __restrict__ pval, int* __restrict__ pidx)
{
    __shared__ ushort ldsB[2 * 64 * 256];       // [hi|lo][row][k] 64KB, swizzled
    const int Nm = counts[0], Nu = counts[1];
    const int b = blockIdx.z;
    const int m0 = blockIdx.y * 64;
    const int half = blockIdx.x;
    const int t = threadIdx.x;
    const int w = t >> 6, l = t & 63;
    const int lm = l & 15, lk = l >> 4;
    const int key = (lm & 7) << 4;

    const int nct = (Nu + 63) >> 6;
    const int hs = (nct + 1) >> 1;
    const int cA = half * hs;
    const int cB = (half ? nct : hs);

    float bestv[4]; int bestn[4];
#pragma unroll
    for (int r = 0; r < 4; ++r) { bestv[r] = -3e38f; bestn[r] = 0; }

    if (m0 < Nm && cA < cB) {
        const char* bytesH = (const char*)hi;
        const char* bytesL = (const char*)lo;
        const size_t bL = (size_t)b * L;
        char* ldsc = (char*)ldsB;

#define STAGE(cc) do { \
    size_t gb = (bL + (size_t)Nm + (size_t)(cc) * 64) * 512; \
    _Pragma("unroll") \
    for (int i = 0; i < 8; ++i) { \
        int j = w * 8 + i; \
        int x = j * 1024 + l * 16; \
        int sx = x ^ (((x >> 9) & 7) << 4); \
        __builtin_amdgcn_global_load_lds((const __attribute__((address_space(1))) unsigned*)(bytesH + gb + sx), \
            (__attribute__((address_space(3))) unsigned*)(ldsc + j * 1024), 16, 0, 0); \
        __builtin_amdgcn_global_load_lds((const __attribute__((address_space(1))) unsigned*)(bytesL + gb + sx), \
            (__attribute__((address_space(3))) unsigned*)(ldsc + 32768 + j * 1024), 16, 0, 0); \
    } \
} while (0)

        STAGE(cA);

        // A fragments into registers: row rA, 8 k-slices of 8 elements at lk*8
        const int rA = m0 + w * 16 + lm;
        bf16x8 ah[8], al[8];
        {
            const ushort* aH = hi + (bL + rA) * C + lk * 8;
            const ushort* aL = lo + (bL + rA) * C + lk * 8;
#pragma unroll
            for (int ks = 0; ks < 8; ++ks) {
                ah[ks] = *(const bf16x8*)(aH + ks * 32);
                al[ks] = *(const bf16x8*)(aL + ks * 32);
            }
        }

        for (int c = cA; c < cB; ++c) {
            asm volatile("s_waitcnt vmcnt(0)" ::: "memory");
            __syncthreads();
            f32x4 acc[4];
#pragma unroll
            for (int nf = 0; nf < 4; ++nf) acc[nf] = (f32x4){0.f, 0.f, 0.f, 0.f};
#pragma unroll
            for (int ks = 0; ks < 8; ++ks) {
                bf16x8 bh[4], bl[4];
#pragma unroll
                for (int nf = 0; nf < 4; ++nf) {
                    int row = nf * 16 + lm;
                    int addr = row * 512 + ((ks * 64 + lk * 16) ^ key);
                    bh[nf] = *(const bf16x8*)(ldsc + addr);
                    bl[nf] = *(const bf16x8*)(ldsc + 32768 + addr);
                }
#pragma unroll
                for (int nf = 0; nf < 4; ++nf)
                    acc[nf] = __builtin_amdgcn_mfma_f32_16x16x32_bf16(ah[ks], bh[nf], acc[nf], 0, 0, 0);
#pragma unroll
                for (int nf = 0; nf < 4; ++nf)
                    acc[nf] = __builtin_amdgcn_mfma_f32_16x16x32_bf16(ah[ks], bl[nf], acc[nf], 0, 0, 0);
#pragma unroll
                for (int nf = 0; nf < 4; ++nf)
                    acc[nf] = __builtin_amdgcn_mfma_f32_16x16x32_bf16(al[ks], bh[nf], acc[nf], 0, 0, 0);
            }
            __syncthreads();
            if (c + 1 < cB) STAGE(c + 1);
            int nbase = c * 64;
#pragma unroll
            for (int r = 0; r < 4; ++r) {
#pragma unroll
                for (int nf = 0; nf < 4; ++nf) {
                    int n = nbase + nf * 16 + lm;
                    float v = acc[nf][r];
                    if (n < Nu && v > bestv[r]) { bestv[r] = v; bestn[r] = n; }
                }
            }
        }
#undef STAGE
    }

    if (m0 >= Nm) return;
    // reduce over the 16 lm lanes (tie -> smaller n), lane lm==0 writes
#pragma unroll
    for (int r = 0; r < 4; ++r) {
        float bv = bestv[r]; int bn = bestn[r];
#pragma unroll
        for (int mk = 1; mk < 16; mk <<= 1) {
            float ov = __shfl_xor(bv, mk, 64);
            int   on = __shfl_xor(bn, mk, 64);
            if (ov > bv || (ov == bv && on < bn)) { bv = ov; bn = on; }
        }
        if (lm == 0) {
            int m = m0 + w * 16 + lk * 4 + r;
            size_t o = ((size_t)(b * 4096 + m)) * 2 + half;
            pval[o] = bv; pidx[o] = bn;
        }
    }
}

// ---------------- Kernel 3b: combine the 2 half-partials ----------------
__global__ __launch_bounds__(256) void argmax_reduce2(
    const float* __restrict__ pval, const int* __restrict__ pidx,
    const int* __restrict__ counts, const int* __restrict__ maskedOrig,
    const int* __restrict__ unmaskOrig, int* __restrict__ idxmap)
{
    int i = blockIdx.x * 256 + threadIdx.x;   // b*4096 + m
    int b = i >> 12, m = i & 4095;
    int Nm = counts[0];
    if (m >= Nm) return;
    size_t base = (size_t)i * 2;
    float bv = pval[base]; int bn = pidx[base];
    float v1 = pval[base + 1];
    if (v1 > bv) { bv = v1; bn = pidx[base + 1]; }   // half1 n's are larger; strict >
    idxmap[(b << 12) + maskedOrig[m]] = unmaskOrig[bn];
}

// ---------------- Kernel 4: weight prep fp32 [co][ci][tau] -> bf16 [co][tau][ci] ----------------
__global__ __launch_bounds__(256) void wprep(
    const float* __restrict__ W1, const float* __restrict__ W2,
    ushort* __restrict__ W1bf, ushort* __restrict__ W2bf)
{
    int gid = blockIdx.x * 256 + threadIdx.x;
    const int N1 = 256 * 512 * 9;
    const int N2 = 256 * 256 * 9;
    if (gid < N1) {
        int ci = gid & 511; int rest = gid >> 9;
        int tau = rest % 9; int co = rest / 9;
        W1bf[gid] = f2bu(W1[((size_t)(co * 512 + ci)) * 9 + tau]);
    } else if (gid < N1 + N2) {
        int g = gid - N1;
        int ci = g & 255; int rest = g >> 8;
        int tau = rest % 9; int co = rest / 9;
        W2bf[g] = f2bu(W2[((size_t)(co * 256 + ci)) * 9 + tau]);
    }
}

// ---------------- Kernel 5: transpose F_c -> inT[b][pix][0:256] bf16 (rows of 512) ----------------
__global__ __launch_bounds__(256) void in_prep1(
    const float* __restrict__ input, ushort* __restrict__ inT)
{
    int b = blockIdx.y;
    int p0 = blockIdx.x * 32;
    __shared__ float tile[256][33];
    int t = threadIdx.x;
    int pq = t & 7;
    for (int cc = 0; cc < 256; cc += 32) {
        int ci = cc + (t >> 3);
        float4 v = *(const float4*)(input + ((size_t)(b * 512 + ci)) * L + p0 + pq * 4);
        tile[ci][pq * 4 + 0] = v.x; tile[ci][pq * 4 + 1] = v.y;
        tile[ci][pq * 4 + 2] = v.z; tile[ci][pq * 4 + 3] = v.w;
    }
    __syncthreads();
    int c8 = t & 31;
    for (int pp = 0; pp < 32; pp += 8) {
        int pixloc = pp + (t >> 5);
        u16x8 u;
#pragma unroll
        for (int j = 0; j < 8; ++j) u[j] = f2bu(tile[c8 * 8 + j][pixloc]);
        *(u16x8*)(inT + ((size_t)(b * 4096 + p0 + pixloc)) * 512 + c8 * 8) = u;
    }
}

// ---------------- Kernel 6: fuse fill inT[b][pix][256:512] = row(p) * row(idx[p]) ----------------
__global__ __launch_bounds__(256) void in_prep2(
    ushort* __restrict__ inT, const int* __restrict__ mask,
    const int* __restrict__ idxmap)
{
    int gid = blockIdx.x * 256 + threadIdx.x;   // 1,048,576 total
    int c8 = gid & 31;
    int pix = (gid >> 5) & 4095;
    int b = gid >> 17;
    u16x8 out8;
    if (mask[pix] > 0) {
        int n = idxmap[(b << 12) + pix];
        const ushort* rp = inT + ((size_t)(b * 4096 + pix)) * 512 + c8 * 8;
        const ushort* rn = inT + ((size_t)(b * 4096 + n)) * 512 + c8 * 8;
        u16x8 a = *(const u16x8*)rp;
        u16x8 bb = *(const u16x8*)rn;
#pragma unroll
        for (int j = 0; j < 8; ++j) out8[j] = f2bu(bu2f(a[j]) * bu2f(bb[j]));
    } else {
#pragma unroll
        for (int j = 0; j < 8; ++j) out8[j] = 0;
    }
    *(u16x8*)(inT + ((size_t)(b * 4096 + pix)) * 512 + 256 + c8 * 8) = out8;
}

// ---------------- Kernel 7: implicit-GEMM 3x3 conv via MFMA ----------------
template<int CKROW>
__global__ __launch_bounds__(256, 2) void conv_mfma(
    const ushort* __restrict__ Abf, const ushort* __restrict__ Wbf,
    float* __restrict__ outF, ushort* __restrict__ outH,
    float* __restrict__ psum, int store32)
{
    __shared__ float4 ldsv[62208 / 16];
    char* lds = (char*)ldsv;
    char* ldsB = lds + 25344;
    const int t = threadIdx.x;
    const int w = t >> 6;
    const int l = t & 63;
    const int lm = l & 15, lk = l >> 4;
    const int b = blockIdx.z;
    const int y0 = blockIdx.x * 4;
    const int c0 = blockIdx.y * 64;
    const int yw = y0 + w;
    const size_t abase = (size_t)b * 4096 * CKROW;

    f32x4 acc[4][4];
#pragma unroll
    for (int g = 0; g < 4; ++g)
#pragma unroll
        for (int nf = 0; nf < 4; ++nf) acc[g][nf] = (f32x4){0.f, 0.f, 0.f, 0.f};

    if (t < 48) {
        int r = t >> 3;
        int cX = ((t >> 2) & 1) ? 65 : 0;
        int k8 = t & 3;
        *(float4*)(lds + (r * 66 + cX) * 64 + ((k8 * 16) ^ ((cX & 3) << 4))) = (float4){0.f,0.f,0.f,0.f};
    }

    const int NKC = CKROW / 32;
    for (int kc = 0; kc < NKC; ++kc) {
        __syncthreads();
        {
            int x = t >> 2;
            int k8 = t & 3;
            int cX = x + 1;
            char* dbase = lds + cX * 64 + ((k8 * 16) ^ ((cX & 3) << 4));
#pragma unroll
            for (int r = 0; r < 6; ++r) {
                int yy = y0 - 1 + r;
                float4 v;
                if (yy >= 0 && yy < 64)
                    v = *(const float4*)(Abf + abase + (size_t)(yy * 64 + x) * CKROW + kc * 32 + k8 * 8);
                else
                    v = (float4){0.f, 0.f, 0.f, 0.f};
                *(float4*)(dbase + r * (66 * 64)) = v;
            }
        }
        {
            int cl = t >> 2;
            int k8 = t & 3;
            char* dbase = ldsB + cl * 64 + ((k8 * 16) ^ ((cl & 3) << 4));
            const ushort* sbase = Wbf + ((size_t)(c0 + cl) * 9) * CKROW + kc * 32 + k8 * 8;
#pragma unroll
            for (int tau = 0; tau < 9; ++tau) {
                *(float4*)(dbase + tau * (64 * 64)) = *(const float4*)(sbase + (size_t)tau * CKROW);
            }
        }
        __syncthreads();
#pragma unroll
        for (int ky = 0; ky < 3; ++ky) {
            int r = w + ky;
#pragma unroll
            for (int kx = 0; kx < 3; ++kx) {
                int tau = ky * 3 + kx;
                bf16x8 bfr[4];
#pragma unroll
                for (int nf = 0; nf < 4; ++nf) {
                    int cl = nf * 16 + lm;
                    bfr[nf] = *(bf16x8*)(ldsB + (tau * 64 + cl) * 64 + ((lk * 16) ^ ((cl & 3) << 4)));
                }
#pragma unroll
                for (int g = 0; g < 4; ++g) {
                    int cX = g * 16 + lm + kx;
                    bf16x8 afr = *(bf16x8*)(lds + (r * 66 + cX) * 64 + ((lk * 16) ^ ((cX & 3) << 4)));
#pragma unroll
                    for (int nf = 0; nf < 4; ++nf)
                        acc[g][nf] = __builtin_amdgcn_mfma_f32_16x16x32_bf16(afr, bfr[nf], acc[g][nf], 0, 0, 0);
                }
            }
        }
    }

    if (store32) {
#pragma unroll
        for (int g = 0; g < 4; ++g)
#pragma unroll
            for (int nf = 0; nf < 4; ++nf) {
                int cout = c0 + nf * 16 + lm;
#pragma unroll
                for (int r = 0; r < 4; ++r) {
                    int pix = yw * 64 + g * 16 + lk * 4 + r;
                    outF[((size_t)(b * 4096 + pix)) * 256 + cout] = acc[g][nf][r];
                }
            }
    } else {
#pragma unroll
        for (int g = 0; g < 4; ++g)
#pragma unroll
            for (int nf = 0; nf < 4; ++nf) {
                int cout = c0 + nf * 16 + lm;
#pragma unroll
                for (int r = 0; r < 4; ++r) {
                    int pix = yw * 64 + g * 16 + lk * 4 + r;
                    outH[((size_t)(b * 4096 + pix)) * 256 + cout] = f2bu(acc[g][nf][r]);
                }
            }
    }

    float s[4], q[4];
#pragma unroll
    for (int nf = 0; nf < 4; ++nf) {
        float ss = 0.f, qq = 0.f;
#pragma unroll
        for (int g = 0; g < 4; ++g)
#pragma unroll
            for (int r = 0; r < 4; ++r) { float v = acc[g][nf][r]; ss += v; qq = fmaf(v, v, qq); }
        ss += __shfl_xor(ss, 16, 64); ss += __shfl_xor(ss, 32, 64);
        qq += __shfl_xor(qq, 16, 64); qq += __shfl_xor(qq, 32, 64);
        s[nf] = ss; q[nf] = qq;
    }
    __syncthreads();
    float* S = (float*)lds;
    float* Q = (float*)(lds + 1024);
    if (l < 16) {
#pragma unroll
        for (int nf = 0; nf < 4; ++nf) {
            S[w * 64 + nf * 16 + l] = s[nf];
            Q[w * 64 + nf * 16 + l] = q[nf];
        }
    }
    __syncthreads();
    if (t < 64) {
        float ts = 0.f, tq = 0.f;
#pragma unroll
        for (int w2 = 0; w2 < 4; ++w2) { ts += S[w2 * 64 + t]; tq += Q[w2 * 64 + t]; }
        size_t o = (((size_t)(b * 256 + c0 + t)) * 16 + blockIdx.x) * 2;
        psum[o] = ts; psum[o + 1] = tq;
    }
}

// ---------------- Kernel 8: partials -> mean/rstd per (b, cout) ----------------
__global__ __launch_bounds__(256) void stats_reduce(
    const float* __restrict__ psum, float* __restrict__ mrs)
{
    int b = blockIdx.x;
    int c = threadIdx.x;
    float s = 0.f, q = 0.f;
    size_t base = ((size_t)(b * 256 + c)) * 16;
    for (int k = 0; k < 16; ++k) { s += psum[(base + k) * 2]; q += psum[(base + k) * 2 + 1]; }
    float mean = s * (1.f / 4096.f);
    float var = q * (1.f / 4096.f) - mean * mean;
    float rs = rsqrtf(var + 1e-5f);
    mrs[(b * 256 + c) * 2] = mean;
    mrs[(b * 256 + c) * 2 + 1] = rs;
}

// ---------------- Kernel 9: hbf = bf16(relu((h_raw - m) * rs)), pixel-major ----------------
__global__ __launch_bounds__(256) void norm1_apply(
    const float* __restrict__ h_raw, const float* __restrict__ mrs,
    ushort* __restrict__ hbf)
{
    int gid = blockIdx.x * 256 + threadIdx.x;
    int c4 = gid & 63;
    int pix = (gid >> 6) & 4095;
    int b = gid >> 18;
    float4 hv = *(const float4*)(h_raw + (((size_t)(b * 4096 + pix)) << 8) + c4 * 4);
    const float4* mv = (const float4*)(mrs + (size_t)b * 512);
    float4 m0 = mv[c4 * 2];
    float4 m1 = mv[c4 * 2 + 1];
    float z0 = (hv.x - m0.x) * m0.y;
    float z1 = (hv.y - m0.z) * m0.w;
    float z2 = (hv.z - m1.x) * m1.y;
    float z3 = (hv.w - m1.z) * m1.w;
    ushort4 o;
    o.x = f2bu(z0 > 0.f ? z0 : 0.f);
    o.y = f2bu(z1 > 0.f ? z1 : 0.f);
    o.z = f2bu(z2 > 0.f ? z2 : 0.f);
    o.w = f2bu(z3 > 0.f ? z3 : 0.f);
    *(ushort4*)(hbf + (((size_t)(b * 4096 + pix)) << 8) + c4 * 4) = o;
}

// ---------------- Kernel 10: out F_c-half = F_c + (res - m) * rs (transpose back) ----------------
__global__ __launch_bounds__(256) void finalize(
    const ushort* __restrict__ resbf, const float* __restrict__ mrs,
    const float* __restrict__ input, float* __restrict__ out)
{
    int b = blockIdx.y;
    int p0 = blockIdx.x * 32;
    __shared__ float tileT[256][33];
    int t = threadIdx.x;
    int c8 = t & 31;
    for (int pp = 0; pp < 32; pp += 8) {
        int pixloc = pp + (t >> 5);
        u16x8 u = *(const u16x8*)(resbf + (((size_t)(b * 4096 + p0 + pixloc)) << 8) + c8 * 8);
#pragma unroll
        for (int j = 0; j < 8; ++j) tileT[c8 * 8 + j][pixloc] = bu2f(u[j]);
    }
    __syncthreads();
    int pq = t & 7;
    for (int cc = 0; cc < 256; cc += 32) {
        int c = cc + (t >> 3);
        float m = mrs[(b * 256 + c) * 2];
        float rs = mrs[(b * 256 + c) * 2 + 1];
        size_t off = ((size_t)(b * 512 + c)) * L + p0 + pq * 4;
        float4 f = *(const float4*)(input + off);
        float4 o;
        o.x = f.x + (tileT[c][pq * 4 + 0] - m) * rs;
        o.y = f.y + (tileT[c][pq * 4 + 1] - m) * rs;
        o.z = f.z + (tileT[c][pq * 4 + 2] - m) * rs;
        o.w = f.w + (tileT[c][pq * 4 + 3] - m) * rs;
        *(float4*)(out + off) = o;
    }
}

// ---------------- Kernel 11: copy F_s to second half of out ----------------
__global__ __launch_bounds__(256) void copy_fs(
    const float* __restrict__ input, float* __restrict__ out)
{
    size_t i = (size_t)blockIdx.x * 256 + threadIdx.x;
    size_t b = i >> 18;
    size_t r = i & 262143;
    size_t o = ((size_t)(b * 512 + 256)) * 1024 + r;
    const float4* s = (const float4*)input;
    float4* d = (float4*)out;
    d[o] = s[o];
}

extern "C" void kernel_launch(void* const* d_in, const int* in_sizes, int n_in,
                              void* d_out, int out_size, void* d_ws, size_t ws_size,
                              hipStream_t stream) {
    const float* input = (const float*)d_in[0];
    const int*   mask  = (const int*)d_in[1];
    const float* W1    = (const float*)d_in[2];
    const float* W2    = (const float*)d_in[4];
    float* out = (float*)d_out;
    (void)in_sizes; (void)n_in; (void)out_size; (void)ws_size;

    char* ob = (char*)d_out;
    char* wp = (char*)d_ws;

    // ---- out-region overlays (phase-ordered) ----
    // Phase I (shift):   fsnh[0:16M) fsnl[16:32M) pval[32:33M) pidx[36:37M)
    // Phase II (conv1):  inT[0:32M)  h_raw[32:64M)
    // Phase III (conv2): hbf[0:16M)
    ushort* fsnh = (ushort*)ob;
    ushort* fsnl = (ushort*)(ob + 16777216);
    float*  pval = (float*)(ob + 33554432);
    int*    pidx = (int*)(ob + 37748736);
    ushort* inT  = (ushort*)ob;
    float*  h_raw = (float*)(ob + 33554432);
    ushort* hbf  = (ushort*)ob;

    // ---- ws regions (~21.1 MB) ----
    ushort* resbf  = (ushort*)wp;                        // 16,777,216
    ushort* W1bf   = (ushort*)(wp + 16777216);           //  2,359,296
    ushort* W2bf   = (ushort*)(wp + 19136512);           //  1,179,648
    float*  psum1  = (float*)(wp + 20316160);            //    262,144
    float*  psum2  = (float*)(wp + 20578304);            //    262,144
    float*  mrs1   = (float*)(wp + 20840448);            //     16,384
    float*  mrs2   = (float*)(wp + 20856832);            //     16,384
    int* counts     = (int*)(wp + 20873216);             //         16
    int* maskedOrig = counts + 4;                        //     16,384
    int* unmaskOrig = maskedOrig + L;                    //     16,384
    int* posOf      = unmaskOrig + L;                    //     16,384
    int* idxmap     = posOf + L;                         //    131,072

    compact_mask<<<1, 256, 0, stream>>>(mask, counts, maskedOrig, unmaskOrig, posOf);
    norm_transpose<<<1024, 256, 0, stream>>>(input, mask, counts, posOf, fsnh, fsnl);
    sim_argmax_v2<<<dim3(2, 64, 8), 256, 0, stream>>>(fsnh, fsnl, counts, pval, pidx);
    argmax_reduce2<<<128, 256, 0, stream>>>(pval, pidx, counts, maskedOrig, unmaskOrig, idxmap);
    wprep<<<6912, 256, 0, stream>>>(W1, W2, W1bf, W2bf);
    in_prep1<<<dim3(128, 8), 256, 0, stream>>>(input, inT);
    in_prep2<<<4096, 256, 0, stream>>>(inT, mask, idxmap);
    conv_mfma<512><<<dim3(16, 4, 8), 256, 0, stream>>>(inT, W1bf, h_raw, (ushort*)nullptr, psum1, 1);
    stats_reduce<<<8, 256, 0, stream>>>(psum1, mrs1);
    norm1_apply<<<8192, 256, 0, stream>>>(h_raw, mrs1, hbf);
    conv_mfma<256><<<dim3(16, 4, 8), 256, 0, stream>>>(hbf, W2bf, (float*)nullptr, resbf, psum2, 0);
    stats_reduce<<<8, 256, 0, stream>>>(psum2, mrs2);
    finalize<<<dim3(128, 8), 256, 0, stream>>>(resbf, mrs2, input, out);
    copy_fs<<<8192, 256, 0, stream>>>(input, out);
}